// Round 10
// baseline (219.696 us; speedup 1.0000x reference)
//
#include <hip/hip_runtime.h>
#include <stdint.h>

// ColBERT MaxSim on MI355X (gfx950), round 16.
// scores[b,c] = sum_n max_s dot(qs[b,n,:], ps[c,s,:])
// qs: (64, 32, 128) f32, ps: (64, 1024, 128) f32, out: (64, 64) f32.
//
// R15 post-mortem: 4 independent acc chains NEUTRAL (111.0 vs 111.5) ->
// dependent-MFMA latency is dead, like barrier-drain (R13). maxsim is
// pinned at ~38 us (2.8x the 13.7 us MFMA wall) across all within-wave
// schedule changes.
//
// R16 theory: WAVE SUPPLY. Grid 512 = 2 blocks/CU = 2 waves/SIMD
// (grid-limited; Occ ~16-21% whenever visible). Per tile-iter per CU the
// LDS port needs ~1850 cyc vs MFMA 2048 cyc -- they only overlap if some
// wave can issue MFMA while others sit in ds_read->lgkmcnt windows. With 2
// waves/SIMD both are often stalled together -> ~35% matrix duty. R13/R15
// changed the within-wave schedule, never the covering-wave count.
// Fix: s-split. Each block does 512 doc tokens (8 x 64-token tiles), grid
// 1024 = 4 blocks/CU = 4 waves/SIMD. Per-CU totals unchanged; covering
// waves double. Keep R13's 2-acc-chain loop: demand ~120 <= 128-reg budget
// of 4 waves/SIMD (allocator's preferred point -- no demotion risk).
// LDS 4 x 32 KB = 128 <= 160 KB.
// Epilogue: per-token maxes must merge across halves BEFORE the token sum.
// Partials -> static g_part; per-(c,bg) monotonic parity counter elects the
// SECOND arriver to combine and write out (first arriver exits -- nobody
// spins, unlike R14). Siblings share an XCD -> combine is L2-local.
// Predict: win = maxsim -> 22-28, dur -> 93-100; neutral ~110 (theory
// dead); >115 = demotion/combine overhead -> revert R13.

typedef __bf16 bf16x8 __attribute__((ext_vector_type(8)));
typedef float floatx16 __attribute__((ext_vector_type(16)));

#define QS_N (64u * 32u * 128u)    // 262144
#define PS_N (64u * 1024u * 128u)  // 8388608

// Static bf16 staging buffer: qs in [0, QS_N), ps in [QS_N, QS_N+PS_N).
__device__ ushort g_bf[QS_N + PS_N];
// Cross-block combine state: per-token-max partials + parity counters.
// g_part[((c*64 + q)*2 + sh)*32 + n]; counters monotonic (graph-replay safe).
__device__ float g_part[64 * 64 * 2 * 32];
__device__ unsigned g_cnt[64 * 8];

__global__ __launch_bounds__(256) void cvt_kernel(const float* __restrict__ qs,
                                                  const float* __restrict__ ps) {
  const int nq4 = QS_N / 4;
  const int n4 = (QS_N + PS_N) / 4;
  int i = blockIdx.x * 256 + threadIdx.x;
  if (i >= n4) return;
  float4 f = (i < nq4) ? ((const float4*)qs)[i] : ((const float4*)ps)[i - nq4];
  union { ushort4 s; struct { __bf16 a, b, c, d; } h; } o;
  o.h.a = (__bf16)f.x; o.h.b = (__bf16)f.y; o.h.c = (__bf16)f.z; o.h.d = (__bf16)f.w;
  ((ushort4*)g_bf)[i] = o.s;
}

__device__ inline float rmax16(const floatx16& a) {
  // Nested fmaxf triples fuse to v_max3_f32.
  float m0 = fmaxf(fmaxf(a[0], a[1]), fmaxf(a[2], a[3]));
  float m1 = fmaxf(fmaxf(a[4], a[5]), fmaxf(a[6], a[7]));
  float m2 = fmaxf(fmaxf(a[8], a[9]), fmaxf(a[10], a[11]));
  float m3 = fmaxf(fmaxf(a[12], a[13]), fmaxf(a[14], a[15]));
  return fmaxf(fmaxf(m0, m1), fmaxf(m2, m3));
}

// global_load_lds: builtin takes AS1/AS3 pointers; C-style casts addrspacecast.
typedef __attribute__((address_space(1))) const void gas_t;
typedef __attribute__((address_space(3))) void las_t;
__device__ inline void gload_lds16(const ushort* g, ushort* l) {
  __builtin_amdgcn_global_load_lds((gas_t*)g, (las_t*)l, 16, 0, 0);
}

#define ZERO16 {0, 0, 0, 0, 0, 0, 0, 0, 0, 0, 0, 0, 0, 0, 0, 0}

__global__ __launch_bounds__(256) void maxsim_kernel(float* __restrict__ out) {
  const ushort* qsb = g_bf;
  const ushort* psb = g_bf + QS_N;

  const int lane = threadIdx.x & 63;
  const int wave = threadIdx.x >> 6;

  // XCD swizzle: all 16 blocks of doc c (8 bg x 2 sh) land on XCD c>>3 ->
  // P_c (256 KB bf16) L2-resident; per-XCD set 8 docs = 2 MB <= 4 MB.
  const int xcd = blockIdx.x & 7;
  const int slot = blockIdx.x >> 3;   // 0..127
  const int c = xcd * 8 + (slot >> 4);
  const int rem = slot & 15;
  const int bg = rem >> 1;            // query-group 0..7
  const int sh = rem & 1;             // s-half 0..1
  const int qb0 = bg * 8 + wave * 2;  // this wave's first query (of 2)

  const int row = lane & 31;          // A-frag: s-row; B-frag: query token n
  const int hi8 = (lane >> 5) * 8;    // K-half selector (elements)

  // Q B-frags straight global->reg (L2/L3-hot, 16B loads), resident all
  // kernel (64 VGPRs): qf[bb][k] = Q[qb0+bb][n=row][k*16 + hi8 + 0..7].
  bf16x8 qf[2][8];
#pragma unroll
  for (int bb = 0; bb < 2; ++bb) {
    const ushort* q = qsb + ((qb0 + bb) * 32 + row) * 128 + hi8;
#pragma unroll
    for (int k = 0; k < 8; ++k)
      qf[bb][k] = *(const bf16x8*)(q + k * 16);
  }

  // P tile double-buffer, 64 tokens/tile = 16 KiB each, A-frag order:
  // sub-tile u (32 rows) at u*8192 B, chunk j (=k) at j*1024 B, lane at 16 B.
  __shared__ __align__(16) ushort lds_p[2][8192];

  // Per-lane global element offset for this block's s-half.
  const int pg_lane = (c * 1024 + sh * 512 + row) * 128 + hi8;

  // Prologue: stage tile 0 (wave w issues global chunks m = 4w..4w+3;
  // m -> sub-tile u = m>>3, chunk j = m&7).
#pragma unroll
  for (int jj = 0; jj < 4; ++jj) {
    const int m = wave * 4 + jj;
    const int u = m >> 3, j = m & 7;
    gload_lds16(psb + pg_lane + u * 32 * 128 + j * 16,
                &lds_p[0][u * 4096 + j * 512]);
  }
  __syncthreads();

  float vmax0 = -3.4e38f, vmax1 = -3.4e38f;
  int cb = 0;

#pragma unroll 1
  for (int t = 0; t < 8; ++t) {
    // Stage tile t+1; latency hides under this tile's 64 MFMAs.
    if (t < 7) {
      const int soff = (t + 1) * 64 * 128;
#pragma unroll
      for (int jj = 0; jj < 4; ++jj) {
        const int m = wave * 4 + jj;
        const int u = m >> 3, j = m & 7;
        gload_lds16(psb + pg_lane + soff + u * 32 * 128 + j * 16,
                    &lds_p[cb ^ 1][u * 4096 + j * 512]);
      }
    }
    // Compute tile t: two 32-row sub-tiles, 2 acc chains (R13 register shape).
    const ushort* lp = &lds_p[cb][0] + lane * 8;
#pragma unroll
    for (int u = 0; u < 2; ++u) {
      floatx16 acc0 = ZERO16, acc1 = ZERO16;
#pragma unroll
      for (int k = 0; k < 8; ++k) {
        bf16x8 af = *(const bf16x8*)(lp + u * 4096 + k * 512);
        acc0 = __builtin_amdgcn_mfma_f32_32x32x16_bf16(af, qf[0][k], acc0, 0, 0, 0);
        acc1 = __builtin_amdgcn_mfma_f32_32x32x16_bf16(af, qf[1][k], acc1, 0, 0, 0);
      }
      vmax0 = fmaxf(vmax0, rmax16(acc0));
      vmax1 = fmaxf(vmax1, rmax16(acc1));
    }
    __syncthreads();
    cb ^= 1;
  }

  // Per-token max for this s-half: lanes l, l^32 hold complementary
  // row-halves of token n = lane&31.
  vmax0 = fmaxf(vmax0, __shfl_xor(vmax0, 32, 64));
  vmax1 = fmaxf(vmax1, __shfl_xor(vmax1, 32, 64));

  // ---- Cross-block combine (the two s-halves of (c,bg)). ----
  if (lane < 32) {
    g_part[((c * 64 + qb0) * 2 + sh) * 32 + lane] = vmax0;
    g_part[((c * 64 + qb0 + 1) * 2 + sh) * 32 + lane] = vmax1;
  }
  __threadfence();   // release: partials visible device-wide
  __syncthreads();   // all 4 waves of this block have published
  __shared__ int s_last;
  if (threadIdx.x == 0) {
    unsigned old = atomicAdd(&g_cnt[c * 8 + bg], 1u);  // monotonic, no reset
    s_last = (int)(old & 1u);                          // second of this pair?
  }
  __syncthreads();
  if (s_last) {
    __threadfence();  // acquire: partner's partials visible
    if (lane < 32) {
      const float* p0 = &g_part[((c * 64 + qb0) * 2) * 32];
      const float* p1 = &g_part[((c * 64 + qb0 + 1) * 2) * 32];
      float m0 = fmaxf(p0[lane], p0[32 + lane]);  // max over s-halves, token n
      float m1 = fmaxf(p1[lane], p1[32 + lane]);
#pragma unroll
      for (int o = 16; o > 0; o >>= 1) {
        m0 += __shfl_xor(m0, o, 64);
        m1 += __shfl_xor(m1, o, 64);
      }
      if (lane == 0) {
        out[(qb0 + 0) * 64 + c] = m0;
        out[(qb0 + 1) * 64 + c] = m1;
      }
    }
  }
}

extern "C" void kernel_launch(void* const* d_in, const int* in_sizes, int n_in,
                              void* d_out, int out_size, void* d_ws, size_t ws_size,
                              hipStream_t stream) {
  const float* qs = (const float*)d_in[0];
  const float* ps = (const float*)d_in[1];
  float* out = (float*)d_out;
  (void)d_ws; (void)ws_size;  // ws poison fill is unconditional; ws gives us nothing

  const int n4 = (int)((QS_N + PS_N) / 4);
  cvt_kernel<<<(n4 + 255) / 256, 256, 0, stream>>>(qs, ps);
  maxsim_kernel<<<dim3(1024), dim3(256), 0, stream>>>(out);
}

// Round 11
// 110.164 us; speedup vs baseline: 1.9943x; 1.9943x over previous
//
#include <hip/hip_runtime.h>
#include <stdint.h>

// ColBERT MaxSim on MI355X (gfx950), round 17.
// scores[b,c] = sum_n max_s dot(qs[b,n,:], ps[c,s,:])
// qs: (64, 32, 128) f32, ps: (64, 1024, 128) f32, out: (64, 64) f32.
//
// R16 post-mortem: s-split regressed hard (VGPR 60! maxsim 150 us) -- the
// cross-block combine epilogue flipped the allocator below qf's footprint.
// 5th confirmation: complexity near the hot loop => allocator demotes qf.
// Reverted to R13 exactly.
//
// Reframe: R13's maxsim ~38 us = 34.4 GFLOP / 38 us = ~905 TF effective --
// EXACTLY the documented ~900 TF ceiling of the 2-barrier gload_lds
// structure (m97 ladder; every in-structure tweak lands 839-912, matching
// R13/R15 neutrality). Documented exit = T4: counted vmcnt, never drain to
// 0 in the main loop, so prefetch loads stay in flight across barriers.
//
// R17: R13 + triple-buffer (3 x 16 KB = 48 KB/block, 2 blocks/CU = 96 KB)
// + depth-2 prefetch + raw s_barrier + counted s_waitcnt:
//   iter t: issue stage(t+2) -> compute buf[t%3] -> vmcnt(4) -> s_barrier
// vmcnt(4): outstanding = stage(t+1) 4 + stage(t+2) 4; in-order retirement
// => the 4 left in flight are stage(t+2), crossing the barrier. stage(t)
// landed-ness: prior iter's vmcnt(4)+barrier. Overwrite safety: stage(t+2)
// target last read at iter t-1, protected by t-1's barrier. Tail: t=14
// vmcnt(0), t=15 computes and exits. Hot loop/qf/epilogue R13-verbatim.
// Predict: win maxsim -> 28-32, dur -> 100-105; neutral ~110 (then the
// plateau is the structure's last word short of a full 8-phase rewrite);
// >115 = race/compiler pathology -> revert R13.

typedef __bf16 bf16x8 __attribute__((ext_vector_type(8)));
typedef float floatx16 __attribute__((ext_vector_type(16)));

#define QS_N (64u * 32u * 128u)    // 262144
#define PS_N (64u * 1024u * 128u)  // 8388608

// Static bf16 staging buffer: qs in [0, QS_N), ps in [QS_N, QS_N+PS_N).
__device__ ushort g_bf[QS_N + PS_N];

__global__ __launch_bounds__(256) void cvt_kernel(const float* __restrict__ qs,
                                                  const float* __restrict__ ps) {
  const int nq4 = QS_N / 4;
  const int n4 = (QS_N + PS_N) / 4;
  int i = blockIdx.x * 256 + threadIdx.x;
  if (i >= n4) return;
  float4 f = (i < nq4) ? ((const float4*)qs)[i] : ((const float4*)ps)[i - nq4];
  union { ushort4 s; struct { __bf16 a, b, c, d; } h; } o;
  o.h.a = (__bf16)f.x; o.h.b = (__bf16)f.y; o.h.c = (__bf16)f.z; o.h.d = (__bf16)f.w;
  ((ushort4*)g_bf)[i] = o.s;
}

__device__ inline float rmax16(const floatx16& a) {
  // Nested fmaxf triples fuse to v_max3_f32.
  float m0 = fmaxf(fmaxf(a[0], a[1]), fmaxf(a[2], a[3]));
  float m1 = fmaxf(fmaxf(a[4], a[5]), fmaxf(a[6], a[7]));
  float m2 = fmaxf(fmaxf(a[8], a[9]), fmaxf(a[10], a[11]));
  float m3 = fmaxf(fmaxf(a[12], a[13]), fmaxf(a[14], a[15]));
  return fmaxf(fmaxf(m0, m1), fmaxf(m2, m3));
}

// global_load_lds: builtin takes AS1/AS3 pointers; C-style casts addrspacecast.
typedef __attribute__((address_space(1))) const void gas_t;
typedef __attribute__((address_space(3))) void las_t;
__device__ inline void gload_lds16(const ushort* g, ushort* l) {
  __builtin_amdgcn_global_load_lds((gas_t*)g, (las_t*)l, 16, 0, 0);
}

#define ZERO16 {0, 0, 0, 0, 0, 0, 0, 0, 0, 0, 0, 0, 0, 0, 0, 0}

__global__ __launch_bounds__(256) void maxsim_kernel(float* __restrict__ out) {
  const ushort* qsb = g_bf;
  const ushort* psb = g_bf + QS_N;

  const int lane = threadIdx.x & 63;
  const int wave = threadIdx.x >> 6;

  // XCD swizzle: the 8 blocks of doc c all land on XCD c>>3 -> P_c (256 KB
  // bf16) L2-resident after the first reader (per-XCD set: 8 docs = 2 MB).
  const int xcd = blockIdx.x & 7;
  const int slot = blockIdx.x >> 3;   // 0..63
  const int c = xcd * 8 + (slot >> 3);
  const int bg = slot & 7;
  const int qb0 = bg * 8 + wave * 2;  // this wave's first query (of 2)

  const int row = lane & 31;          // A-frag: s-row; B-frag: query token n
  const int hi8 = (lane >> 5) * 8;    // K-half selector (elements)

  // Q B-frags straight global->reg (L2/L3-hot, 16B loads), resident all
  // kernel (64 VGPRs): qf[bb][k] = Q[qb0+bb][n=row][k*16 + hi8 + 0..7].
  bf16x8 qf[2][8];
#pragma unroll
  for (int bb = 0; bb < 2; ++bb) {
    const ushort* q = qsb + ((qb0 + bb) * 32 + row) * 128 + hi8;
#pragma unroll
    for (int k = 0; k < 8; ++k)
      qf[bb][k] = *(const bf16x8*)(q + k * 16);
  }

  // P tile TRIPLE buffer, 64 tokens/tile = 16 KiB each, A-frag order:
  // sub-tile u (32 rows) at u*8192 B, chunk j (=k) at j*1024 B, lane at 16 B.
  __shared__ __align__(16) ushort lds_p[3][8192];

  // Per-lane global element offset (tile tt adds tt*8192 elements).
  const int pg_lane = (c * 1024 + row) * 128 + hi8;

  // Wave w issues global chunks m = 4w..4w+3 (u = m>>3, j = m&7).
#define STAGE(L, tt)                                                          \
  _Pragma("unroll") for (int jj = 0; jj < 4; ++jj) {                          \
    const int m = wave * 4 + jj;                                              \
    const int u = m >> 3, j = m & 7;                                          \
    gload_lds16(psb + pg_lane + (tt) * 8192 + u * 32 * 128 + j * 16,          \
                (L) + u * 4096 + j * 512);                                    \
  }

  ushort* pA = &lds_p[0][0];  // current compute tile
  ushort* pB = &lds_p[1][0];  // tile t+1 (in flight / landed)
  ushort* pC = &lds_p[2][0];  // tile t+2 (staging target)

  // Prologue: stage tiles 0 and 1 (8 loads outstanding), wait for tile 0
  // only (vmcnt(4): tile-1's 4 loads stay in flight), collective barrier.
  STAGE(pA, 0)
  STAGE(pB, 1)
  asm volatile("s_waitcnt vmcnt(4)" ::: "memory");
  __builtin_amdgcn_s_barrier();

  float vmax0 = -3.4e38f, vmax1 = -3.4e38f;

#pragma unroll 1
  for (int t = 0; t < 16; ++t) {
    // Issue stage(t+2) into pC BEFORE compute: overlaps compute(t) and
    // compute(t+1) (~2 phases to land). pC's last readers were iter t-1,
    // protected by that iteration's barrier.
    if (t + 2 < 16) {
      STAGE(pC, t + 2)
    }
    // Compute tile t from pA (R13-verbatim: 2 sub-tiles, 2 acc chains).
    // stage(t) landed: prior iteration's vmcnt+barrier.
    const ushort* lp = pA + lane * 8;
#pragma unroll
    for (int u = 0; u < 2; ++u) {
      floatx16 acc0 = ZERO16, acc1 = ZERO16;
#pragma unroll
      for (int k = 0; k < 8; ++k) {
        bf16x8 af = *(const bf16x8*)(lp + u * 4096 + k * 512);
        acc0 = __builtin_amdgcn_mfma_f32_32x32x16_bf16(af, qf[0][k], acc0, 0, 0, 0);
        acc1 = __builtin_amdgcn_mfma_f32_32x32x16_bf16(af, qf[1][k], acc1, 0, 0, 0);
      }
      vmax0 = fmaxf(vmax0, rmax16(acc0));
      vmax1 = fmaxf(vmax1, rmax16(acc1));
    }
    // Counted wait: own stage(t+1) landed (in-order retirement leaves only
    // stage(t+2)'s 4 loads in flight ACROSS the barrier -- the T4 lever).
    // Tail: t=14 has no stage(16), so drain to 0 for stage(15); t=15 exits.
    if (t + 2 < 16) {
      asm volatile("s_waitcnt vmcnt(4)" ::: "memory");
    } else if (t + 1 < 16) {
      asm volatile("s_waitcnt vmcnt(0)" ::: "memory");
    }
    if (t + 1 < 16) __builtin_amdgcn_s_barrier();
    // Rotate buffers: pA <- pB (next compute), pB <- pC, pC <- old pA.
    ushort* tmp = pA; pA = pB; pB = pC; pC = tmp;
  }

  // acc D-layout: col = lane&31 = token n; lanes l, l^32 hold complementary
  // row-halves -> max-merge, then butterfly-sum the 32 tokens.
  vmax0 = fmaxf(vmax0, __shfl_xor(vmax0, 32, 64));
  vmax1 = fmaxf(vmax1, __shfl_xor(vmax1, 32, 64));
#pragma unroll
  for (int o = 16; o > 0; o >>= 1) {
    vmax0 += __shfl_xor(vmax0, o, 64);
    vmax1 += __shfl_xor(vmax1, o, 64);
  }
  if (lane == 0) {
    out[(qb0 + 0) * 64 + c] = vmax0;
    out[(qb0 + 1) * 64 + c] = vmax1;
  }
}

extern "C" void kernel_launch(void* const* d_in, const int* in_sizes, int n_in,
                              void* d_out, int out_size, void* d_ws, size_t ws_size,
                              hipStream_t stream) {
  const float* qs = (const float*)d_in[0];
  const float* ps = (const float*)d_in[1];
  float* out = (float*)d_out;
  (void)d_ws; (void)ws_size;  // ws poison fill is unconditional; ws gives us nothing

  const int n4 = (int)((QS_N + PS_N) / 4);
  cvt_kernel<<<(n4 + 255) / 256, 256, 0, stream>>>(qs, ps);
  maxsim_kernel<<<dim3(512), dim3(256), 0, stream>>>(out);
}